// Round 11
// baseline (217.057 us; speedup 1.0000x reference)
//
#include <hip/hip_runtime.h>
#include <hip/hip_bf16.h>
#include <stdint.h>

#define DIM 1024
#define SEQ 2048
#define TOK 8192   // 4*2048

typedef __hip_bfloat16 bf16;
using bf16x8 = __attribute__((ext_vector_type(8))) short;
using bf16x4 = __attribute__((ext_vector_type(4))) short;
using f32x4  = __attribute__((ext_vector_type(4))) float;

struct __align__(8) bh4 { bf16 a, b, c, d; };

__device__ __forceinline__ void g2lds16(const void* g, void* l) {
    __builtin_amdgcn_global_load_lds(
        (const __attribute__((address_space(1))) void*)g,
        (__attribute__((address_space(3))) void*)l,
        16, 0, 0);
}

__device__ __forceinline__ short bfb(float f) {
    __hip_bfloat16 h = __float2bfloat16(f);
    return *reinterpret_cast<short*>(&h);
}

// ---------------- cast fp32 -> bf16 (x and the 4 weight matrices) ----------------
__global__ __launch_bounds__(256) void cast_all_kernel(
    const float* __restrict__ x,  const float* __restrict__ wq,
    const float* __restrict__ wk, const float* __restrict__ wv,
    const float* __restrict__ wo, bf16* __restrict__ xb, bf16* __restrict__ wb)
{
    const long idx = (long)blockIdx.x * 256 + threadIdx.x;
    const long e = idx * 4;
    const float* src;
    bf16* dst;
    if (e < 8388608L) { src = x + e; dst = xb + e; }
    else {
        const long j = e - 8388608L;
        const int  w = (int)(j >> 20);
        const long off = j & 1048575L;
        src = ((w == 0) ? wq : (w == 1) ? wk : (w == 2) ? wv : wo) + off;
        dst = wb + ((long)w << 20) + off;
    }
    const float4 v = *(const float4*)src;
    bh4 o;
    o.a = __float2bfloat16(v.x); o.b = __float2bfloat16(v.y);
    o.c = __float2bfloat16(v.z); o.d = __float2bfloat16(v.w);
    *(bh4*)dst = o;
}

// ---------------- C = A @ B^T  (A [M,1024] bf16, B [N,1024] bf16) ----------------
// 128x128 tile, 4 waves x 64x64, acc[4][4], T2 XOR-swizzle (byte ^= (row&7)<<4):
// linear global_load_lds dest, pre-swizzled global source col, swizzled reads.
// MODE 0: fused QKV (N=3072): +bias; Q pre-scaled by 1/sqrt(Dh)*log2e; V -> Vt.
// MODE 1: out-proj (N=1024): +bias +fp32 residual -> fp32 out
template<int MODE>
__global__ __launch_bounds__(256) void gemm_bt_kernel(
    const bf16* __restrict__ A, const bf16* __restrict__ B,
    const float* __restrict__ bias0, const float* __restrict__ bias1,
    const float* __restrict__ bias2, const float* __restrict__ xres,
    bf16* __restrict__ outQ, bf16* __restrict__ outK, bf16* __restrict__ outVt,
    float* __restrict__ outO)
{
    __shared__ __align__(16) bf16 As[128 * 64];   // 16 KB, swizzled rows of 128B
    __shared__ __align__(16) bf16 Bs[128 * 64];   // 16 KB
    const int tid  = threadIdx.x;
    const int wave = tid >> 6;
    const int lane = tid & 63;
    const int bm = blockIdx.x;
    const int bn = blockIdx.y;
    const int wm = (wave >> 1) * 64;
    const int wn = (wave & 1) * 64;
    const int lcol = lane & 15;
    const int lrow = lane >> 4;
    const int l8 = lane >> 3, l7 = lane & 7;
    const int swz = (l7 ^ l8) * 8;       // pre-swizzled source col (elements)

    f32x4 acc[4][4] = {};

    const bf16* Ab = A + ((long)bm * 128 + wave * 32 + l8) * 1024 + swz;
    const bf16* Bb = B + ((long)bn * 128 + wave * 32 + l8) * 1024 + swz;
    char* AsW = (char*)As + (wave * 32) * 128;
    char* BsW = (char*)Bs + (wave * 32) * 128;

    for (int kt = 0; kt < 1024; kt += 64) {
        #pragma unroll
        for (int i = 0; i < 4; ++i) {
            g2lds16(Ab + (long)i * 8 * 1024 + kt, AsW + i * 1024);
            g2lds16(Bb + (long)i * 8 * 1024 + kt, BsW + i * 1024);
        }
        __syncthreads();
        bf16x8 af[4][2], bfr[4][2];
        #pragma unroll
        for (int m = 0; m < 4; ++m) {
            const int row = wm + m * 16 + lcol;
            #pragma unroll
            for (int kk = 0; kk < 2; ++kk) {
                const int off = (row * 128 + kk * 64 + lrow * 16) ^ ((row & 7) << 4);
                af[m][kk] = *(const bf16x8*)((const char*)As + off);
            }
        }
        #pragma unroll
        for (int n = 0; n < 4; ++n) {
            const int row = wn + n * 16 + lcol;
            #pragma unroll
            for (int kk = 0; kk < 2; ++kk) {
                const int off = (row * 128 + kk * 64 + lrow * 16) ^ ((row & 7) << 4);
                bfr[n][kk] = *(const bf16x8*)((const char*)Bs + off);
            }
        }
        #pragma unroll
        for (int kk = 0; kk < 2; ++kk)
            #pragma unroll
            for (int m = 0; m < 4; ++m)
                #pragma unroll
                for (int n = 0; n < 4; ++n)
                    acc[m][n] = __builtin_amdgcn_mfma_f32_16x16x32_bf16(
                        af[m][kk], bfr[n][kk], acc[m][n], 0, 0, 0);
        __syncthreads();
    }

    const int rbase = lrow * 4;
    if (MODE == 0) {
        const int which = bn >> 3;   // 0=Q 1=K 2=V (block-uniform)
        const float* bias = (which == 0) ? bias0 : (which == 1) ? bias1 : bias2;
        const float QSCALE = 0.125f * 1.44269504089f;  // fold softmax scale into Q
        #pragma unroll
        for (int m = 0; m < 4; ++m) {
            const long gr = (long)bm * 128 + wm + m * 16 + rbase;
            #pragma unroll
            for (int n = 0; n < 4; ++n) {
                const int gc = bn * 128 + wn + n * 16 + lcol;
                const int nn = gc & 1023;
                const float bv_ = bias[nn];
                #pragma unroll
                for (int r = 0; r < 4; ++r) {
                    const long t = gr + r;
                    const float v = acc[m][n][r] + bv_;
                    if (which == 0)      outQ[t * 1024 + nn] = __float2bfloat16(v * QSCALE);
                    else if (which == 1) outK[t * 1024 + nn] = __float2bfloat16(v);
                    else {
                        const long bb = t >> 11;       // batch
                        const long s  = t & 2047;      // seq pos
                        const int  hh = nn >> 6, dh = nn & 63;
                        outVt[((bb * 16 + hh) * 64 + dh) * 2048 + s] = __float2bfloat16(v);
                    }
                }
            }
        }
    } else {
        #pragma unroll
        for (int m = 0; m < 4; ++m) {
            const long gr = (long)bm * 128 + wm + m * 16 + rbase;
            #pragma unroll
            for (int n = 0; n < 4; ++n) {
                const int gc = bn * 128 + wn + n * 16 + lcol;
                const float bv_ = bias0[gc];
                #pragma unroll
                for (int r = 0; r < 4; ++r) {
                    const long t = gr + r;
                    outO[t * 1024 + gc] = acc[m][n][r] + bv_ + xres[t * 1024 + gc];
                }
            }
        }
    }
}

// ---------------- attn sub-tile compute (inlined twice per iteration) ----------
__device__ __forceinline__ void attn_subtile(
    const char* Kp, const char* Vp, const bf16x8 (&qf)[2], const bf16x8& ONES,
    f32x4 (&o_acc)[4], f32x4& l_acc,
    int kbase, int qtb, int q0, int lcol, int lrow)
{
    // --- S^T sub-tile: mfma(K, Q), K-frag from swizzled LDS ---
    f32x4 s_acc[4] = {};
    __builtin_amdgcn_s_setprio(1);
    #pragma unroll
    for (int n = 0; n < 4; ++n) {
        const int krow = n * 16 + lcol;
        #pragma unroll
        for (int kk = 0; kk < 2; ++kk) {
            const int off = (krow * 128 + kk * 64 + lrow * 16) ^ ((krow & 7) << 4);
            bf16x8 kf = *(const bf16x8*)(Kp + off);
            s_acc[n] = __builtin_amdgcn_mfma_f32_16x16x32_bf16(kf, qf[kk], s_acc[n], 0, 0, 0);
        }
    }
    __builtin_amdgcn_s_setprio(0);
    // --- causal mask (diagonal sub-tile only); s_acc[n][r] holds
    //     actual k = kbase + (n>>1)*32 + lrow*8 + (n&1)*4 + r (K staged permuted) ---
    if (kbase == qtb) {
        const int qg = q0 + lcol;
        #pragma unroll
        for (int n = 0; n < 4; ++n)
            #pragma unroll
            for (int r = 0; r < 4; ++r) {
                const int ka = kbase + ((n >> 1) << 5) + lrow * 8 + ((n & 1) << 2) + r;
                if (ka > qg) s_acc[n][r] = -1e30f;
            }
    }
    // --- fixed-m softmax numerator: p = exp2(s) ---
    #pragma unroll
    for (int n = 0; n < 4; ++n)
        #pragma unroll
        for (int r = 0; r < 4; ++r)
            s_acc[n][r] = exp2f(s_acc[n][r]);
    // --- pack P into two K=32 A-frags (k order = actual k, identity) ---
    bf16x8 paA, paB;
    #pragma unroll
    for (int r = 0; r < 4; ++r) {
        paA[r]     = bfb(s_acc[0][r]);
        paA[r + 4] = bfb(s_acc[1][r]);
        paB[r]     = bfb(s_acc[2][r]);
        paB[r + 4] = bfb(s_acc[3][r]);
    }
    // --- PV + row-sum, all on the matrix pipe ---
    __builtin_amdgcn_s_setprio(1);
    l_acc = __builtin_amdgcn_mfma_f32_16x16x32_bf16(paA, ONES, l_acc, 0, 0, 0);
    l_acc = __builtin_amdgcn_mfma_f32_16x16x32_bf16(paB, ONES, l_acc, 0, 0, 0);
    #pragma unroll
    for (int d = 0; d < 4; ++d) {
        const int vrow = d * 16 + lcol;
        const int offA = (vrow * 128 + lrow * 16) ^ ((vrow & 7) << 4);
        const int offB = offA ^ 64;   // +64B = k half 2 (bit 6 untouched by swizzle)
        bf16x8 vfA = *(const bf16x8*)(Vp + offA);
        o_acc[d] = __builtin_amdgcn_mfma_f32_16x16x32_bf16(paA, vfA, o_acc[d], 0, 0, 0);
        bf16x8 vfB = *(const bf16x8*)(Vp + offB);
        o_acc[d] = __builtin_amdgcn_mfma_f32_16x16x32_bf16(paB, vfB, o_acc[d], 0, 0, 0);
    }
    __builtin_amdgcn_s_setprio(0);
}

// ---------------- causal flash attention v8 ---------------
// FUSED dual-q-tile: each block owns q-tiles qtA=pr and qtB=31-pr and runs ONE
// k-loop of 32-pr iterations x 64 k. Per iteration: stage K/V tile once into
// single-64k double-buffered LDS (32 KB total -> 5 blocks/CU, ~20 waves/CU),
// compute sub-tile for A (if kbase <= qtbA, block-uniform) and for B (always).
// Halves staging + barriers vs sequential halves; all 1024 blocks co-resident.
// T1 XCD remap (8 heads/XCD), T2 swizzled LDS, K-row permutation for K=32 PV,
// fixed-m exp2 softmax, l via MFMA-vs-ONES: all unchanged from v7.
__global__ __launch_bounds__(256) void attn_kernel(
    const bf16* __restrict__ Qb, const bf16* __restrict__ Kb,
    const bf16* __restrict__ Vt, bf16* __restrict__ ctx)
{
    __shared__ __align__(16) bf16 Ks[2][4096];   // [buf][64 rows x 64 cols] 16 KB
    __shared__ __align__(16) bf16 Vs[2][4096];   // 16 KB
    const int tid = threadIdx.x, wv = tid >> 6, lane = tid & 63;
    const int id  = blockIdx.y * 16 + blockIdx.x;   // physical dispatch order
    const int lid = (id & 7) * 128 + (id >> 3);     // XCD-chunked logical id
    const int bh  = lid >> 4;                       // 0..63 (8 heads per XCD)
    const int pr  = lid & 15;                       // 0..15
    const int b = bh >> 4, h = bh & 15;
    const bf16* Qh = Qb + (long)b * SEQ * DIM + h * 64;
    const bf16* Kh = Kb + (long)b * SEQ * DIM + h * 64;
    const bf16* Vh = Vt + (long)bh * 64 * SEQ;
    const int lcol = lane & 15;       // q (C col) / fragment row selector
    const int lrow = lane >> 4;       // 0..3
    const int l8 = lane >> 3, l7 = lane & 7;
    const int swz = (l7 ^ l8) * 8;
    const int kprow = (wv >> 1) * 32 + (l8 >> 2) * 8 + (wv & 1) * 4 + (l8 & 3); // i=0; +16 for i=1
    const bf16* kSrc = Kh + (long)kprow * DIM + swz;            // + (k + i*16)*DIM
    const bf16* vSrc = Vh + (long)(wv * 16 + l8) * SEQ + swz;   // + k + i*8*SEQ

    const bf16x8 ONES = { (short)0x3F80, (short)0x3F80, (short)0x3F80, (short)0x3F80,
                          (short)0x3F80, (short)0x3F80, (short)0x3F80, (short)0x3F80 };

    const int qtA = pr, qtB = 31 - pr;
    const int qtbA = qtA * 64, qtbB = qtB * 64;
    const int q0A = qtbA + wv * 16, q0B = qtbB + wv * 16;

    bf16x8 qfA[2], qfB[2];
    #pragma unroll
    for (int kk = 0; kk < 2; ++kk) {
        qfA[kk] = *(const bf16x8*)&Qh[(long)(q0A + lcol) * DIM + kk * 32 + lrow * 8];
        qfB[kk] = *(const bf16x8*)&Qh[(long)(q0B + lcol) * DIM + kk * 32 + lrow * 8];
    }

    f32x4 oA[4] = {}, oB[4] = {};
    f32x4 lA = {}, lB = {};
    const int itn = qtB + 1;   // 64-k iterations (covers both tiles)

    // prologue: stage tile 0 into buffer 0
    #pragma unroll
    for (int i = 0; i < 2; ++i) {
        g2lds16(kSrc + (long)(i * 16) * DIM, (char*)Ks[0] + wv * 2048 + i * 1024);
        g2lds16(vSrc + (long)i * 8 * SEQ,    (char*)Vs[0] + wv * 2048 + i * 1024);
    }
    __syncthreads();
    for (int t = 0; t < itn; ++t) {
        // prefetch iteration t+1 into the other buffer (its readers finished
        // before the barrier we already passed); loads fly during compute(t)
        if (t + 1 < itn) {
            const long ko = (long)(t + 1) * 64;
            char* dK = (char*)Ks[(t + 1) & 1] + wv * 2048;
            char* dV = (char*)Vs[(t + 1) & 1] + wv * 2048;
            #pragma unroll
            for (int i = 0; i < 2; ++i) {
                g2lds16(kSrc + (ko + i * 16) * DIM, dK + i * 1024);
                g2lds16(vSrc + ko + (long)i * 8 * SEQ, dV + i * 1024);
            }
        }
        const int kbase = t * 64;
        const char* Kp = (const char*)Ks[t & 1];
        const char* Vp = (const char*)Vs[t & 1];
        if (kbase <= qtbA)   // block-uniform branch
            attn_subtile(Kp, Vp, qfA, ONES, oA, lA, kbase, qtbA, q0A, lcol, lrow);
        attn_subtile(Kp, Vp, qfB, ONES, oB, lB, kbase, qtbB, q0B, lcol, lrow);
        __syncthreads();   // readers of buf[t&1] done + staging of t+1 drained
    }
    // --- epilogue: l in same C-layout as o -> lane-local divide; write both tiles ---
    #pragma unroll
    for (int d = 0; d < 4; ++d)
        #pragma unroll
        for (int r = 0; r < 4; ++r) {
            const long rowA = (long)(b * SEQ + q0A + lrow * 4 + r);
            ctx[rowA * DIM + h * 64 + d * 16 + lcol] = __float2bfloat16(oA[d][r] / lA[r]);
            const long rowB = (long)(b * SEQ + q0B + lrow * 4 + r);
            ctx[rowB * DIM + h * 64 + d * 16 + lcol] = __float2bfloat16(oB[d][r] / lB[r]);
        }
}

// ---------------- row LayerNorm, in place on d_out ----------------
__global__ __launch_bounds__(256) void ln_kernel(float* __restrict__ io,
    const float* __restrict__ gamma, const float* __restrict__ beta)
{
    float* p = io + (long)blockIdx.x * 1024;
    const int tid = threadIdx.x;
    const int c = tid * 4;
    const float4 v = *(const float4*)&p[c];
    float s  = v.x + v.y + v.z + v.w;
    float s2 = v.x * v.x + v.y * v.y + v.z * v.z + v.w * v.w;
    #pragma unroll
    for (int off = 1; off < 64; off <<= 1) {
        s  += __shfl_xor(s, off);
        s2 += __shfl_xor(s2, off);
    }
    __shared__ float red[8];
    if ((tid & 63) == 0) { red[tid >> 6] = s; red[4 + (tid >> 6)] = s2; }
    __syncthreads();
    s  = red[0] + red[1] + red[2] + red[3];
    s2 = red[4] + red[5] + red[6] + red[7];
    const float mu = s * (1.0f / 1024.0f);
    const float var = fmaxf(s2 * (1.0f / 1024.0f) - mu * mu, 0.0f);
    const float rstd = rsqrtf(var + 1e-5f);
    const float4 g  = *(const float4*)&gamma[c];
    const float4 bb = *(const float4*)&beta[c];
    float4 o;
    o.x = (v.x - mu) * rstd * g.x + bb.x;
    o.y = (v.y - mu) * rstd * g.y + bb.y;
    o.z = (v.z - mu) * rstd * g.z + bb.z;
    o.w = (v.w - mu) * rstd * g.w + bb.w;
    *(float4*)&p[c] = o;
}

extern "C" void kernel_launch(void* const* d_in, const int* in_sizes, int n_in,
                              void* d_out, int out_size, void* d_ws, size_t ws_size,
                              hipStream_t stream)
{
    const float* x     = (const float*)d_in[0];
    const float* Wq    = (const float*)d_in[1];
    const float* bq    = (const float*)d_in[2];
    const float* Wk    = (const float*)d_in[3];
    const float* bk    = (const float*)d_in[4];
    const float* Wv    = (const float*)d_in[5];
    const float* bv    = (const float*)d_in[6];
    const float* Wo    = (const float*)d_in[7];
    const float* bo    = (const float*)d_in[8];
    const float* gamma = (const float*)d_in[9];
    const float* beta  = (const float*)d_in[10];
    float* out = (float*)d_out;

    char* ws = (char*)d_ws;
    bf16* xb  = (bf16*)(ws);                          // 16 MB  x bf16 [8192,1024]
    bf16* wb  = (bf16*)(ws + (16L << 20));            //  8 MB  Wq,Wk,Wv,Wo bf16 stacked
    bf16* Qb  = (bf16*)(ws + (24L << 20));            // 16 MB  [8192,1024]
    bf16* Kb  = (bf16*)(ws + (40L << 20));            // 16 MB
    bf16* Vt  = (bf16*)(ws + (56L << 20));            // 16 MB  [64][64][2048]
    bf16* ctx = (bf16*)(ws + (72L << 20));            // 16 MB  [8192,1024]

    cast_all_kernel<<<12288, 256, 0, stream>>>(x, Wq, Wk, Wv, Wo, xb, wb);
    gemm_bt_kernel<0><<<dim3(64, 24), 256, 0, stream>>>(
        xb, wb, bq, bk, bv, nullptr, Qb, Kb, Vt, nullptr);
    attn_kernel<<<dim3(16, 64), 256, 0, stream>>>(Qb, Kb, Vt, ctx);
    gemm_bt_kernel<1><<<dim3(64, 8), 256, 0, stream>>>(
        ctx, wb + 3L * 1048576, bo, nullptr, nullptr, x, nullptr, nullptr, nullptr, out);
    ln_kernel<<<8192, 256, 0, stream>>>(out, gamma, beta);
}

// Round 12
// 196.681 us; speedup vs baseline: 1.1036x; 1.1036x over previous
//
#include <hip/hip_runtime.h>
#include <hip/hip_bf16.h>
#include <stdint.h>

#define DIM 1024
#define SEQ 2048
#define TOK 8192   // 4*2048

typedef __hip_bfloat16 bf16;
using bf16x8 = __attribute__((ext_vector_type(8))) short;
using bf16x4 = __attribute__((ext_vector_type(4))) short;
using f32x4  = __attribute__((ext_vector_type(4))) float;

struct __align__(8) bh4 { bf16 a, b, c, d; };

__device__ __forceinline__ void g2lds16(const void* g, void* l) {
    __builtin_amdgcn_global_load_lds(
        (const __attribute__((address_space(1))) void*)g,
        (__attribute__((address_space(3))) void*)l,
        16, 0, 0);
}

// raw HW 2^x (exp2f without -ffast-math goes through OCML fixup code)
__device__ __forceinline__ float hexp2(float x) {
    float r;
    asm("v_exp_f32 %0, %1" : "=v"(r) : "v"(x));
    return r;
}
// packed f32x2 -> bf16x2 RNE in ONE instruction (__float2bfloat16 is ~6-instr
// software RNE; compiler cannot fuse those into cvt_pk)
__device__ __forceinline__ unsigned cvtpk(float lo, float hi) {
    unsigned r;
    asm("v_cvt_pk_bf16_f32 %0, %1, %2" : "=v"(r) : "v"(lo), "v"(hi));
    return r;
}

__device__ __forceinline__ short bfb(float f) {
    __hip_bfloat16 h = __float2bfloat16(f);
    return *reinterpret_cast<short*>(&h);
}

// ---------------- cast fp32 -> bf16 (x and the 4 weight matrices) ----------------
__global__ __launch_bounds__(256) void cast_all_kernel(
    const float* __restrict__ x,  const float* __restrict__ wq,
    const float* __restrict__ wk, const float* __restrict__ wv,
    const float* __restrict__ wo, bf16* __restrict__ xb, bf16* __restrict__ wb)
{
    const long idx = (long)blockIdx.x * 256 + threadIdx.x;
    const long e = idx * 4;
    const float* src;
    bf16* dst;
    if (e < 8388608L) { src = x + e; dst = xb + e; }
    else {
        const long j = e - 8388608L;
        const int  w = (int)(j >> 20);
        const long off = j & 1048575L;
        src = ((w == 0) ? wq : (w == 1) ? wk : (w == 2) ? wv : wo) + off;
        dst = wb + ((long)w << 20) + off;
    }
    const float4 v = *(const float4*)src;
    bh4 o;
    o.a = __float2bfloat16(v.x); o.b = __float2bfloat16(v.y);
    o.c = __float2bfloat16(v.z); o.d = __float2bfloat16(v.w);
    *(bh4*)dst = o;
}

// ---------------- C = A @ B^T  (A [M,1024] bf16, B [N,1024] bf16) ----------------
// 128x128 tile, 4 waves x 64x64, acc[4][4], T2 XOR-swizzle (byte ^= (row&7)<<4):
// linear global_load_lds dest, pre-swizzled global source col, swizzled reads.
// MODE 0: fused QKV (N=3072): +bias; Q pre-scaled by 1/sqrt(Dh)*log2e; V -> Vt.
// MODE 1: out-proj (N=1024): +bias +fp32 residual -> fp32 out
template<int MODE>
__global__ __launch_bounds__(256) void gemm_bt_kernel(
    const bf16* __restrict__ A, const bf16* __restrict__ B,
    const float* __restrict__ bias0, const float* __restrict__ bias1,
    const float* __restrict__ bias2, const float* __restrict__ xres,
    bf16* __restrict__ outQ, bf16* __restrict__ outK, bf16* __restrict__ outVt,
    float* __restrict__ outO)
{
    __shared__ __align__(16) bf16 As[128 * 64];   // 16 KB, swizzled rows of 128B
    __shared__ __align__(16) bf16 Bs[128 * 64];   // 16 KB
    const int tid  = threadIdx.x;
    const int wave = tid >> 6;
    const int lane = tid & 63;
    const int bm = blockIdx.x;
    const int bn = blockIdx.y;
    const int wm = (wave >> 1) * 64;
    const int wn = (wave & 1) * 64;
    const int lcol = lane & 15;
    const int lrow = lane >> 4;
    const int l8 = lane >> 3, l7 = lane & 7;
    const int swz = (l7 ^ l8) * 8;       // pre-swizzled source col (elements)

    f32x4 acc[4][4] = {};

    const bf16* Ab = A + ((long)bm * 128 + wave * 32 + l8) * 1024 + swz;
    const bf16* Bb = B + ((long)bn * 128 + wave * 32 + l8) * 1024 + swz;
    char* AsW = (char*)As + (wave * 32) * 128;
    char* BsW = (char*)Bs + (wave * 32) * 128;

    for (int kt = 0; kt < 1024; kt += 64) {
        #pragma unroll
        for (int i = 0; i < 4; ++i) {
            g2lds16(Ab + (long)i * 8 * 1024 + kt, AsW + i * 1024);
            g2lds16(Bb + (long)i * 8 * 1024 + kt, BsW + i * 1024);
        }
        __syncthreads();
        bf16x8 af[4][2], bfr[4][2];
        #pragma unroll
        for (int m = 0; m < 4; ++m) {
            const int row = wm + m * 16 + lcol;
            #pragma unroll
            for (int kk = 0; kk < 2; ++kk) {
                const int off = (row * 128 + kk * 64 + lrow * 16) ^ ((row & 7) << 4);
                af[m][kk] = *(const bf16x8*)((const char*)As + off);
            }
        }
        #pragma unroll
        for (int n = 0; n < 4; ++n) {
            const int row = wn + n * 16 + lcol;
            #pragma unroll
            for (int kk = 0; kk < 2; ++kk) {
                const int off = (row * 128 + kk * 64 + lrow * 16) ^ ((row & 7) << 4);
                bfr[n][kk] = *(const bf16x8*)((const char*)Bs + off);
            }
        }
        #pragma unroll
        for (int kk = 0; kk < 2; ++kk)
            #pragma unroll
            for (int m = 0; m < 4; ++m)
                #pragma unroll
                for (int n = 0; n < 4; ++n)
                    acc[m][n] = __builtin_amdgcn_mfma_f32_16x16x32_bf16(
                        af[m][kk], bfr[n][kk], acc[m][n], 0, 0, 0);
        __syncthreads();
    }

    const int rbase = lrow * 4;
    if (MODE == 0) {
        const int which = bn >> 3;   // 0=Q 1=K 2=V (block-uniform)
        const float* bias = (which == 0) ? bias0 : (which == 1) ? bias1 : bias2;
        const float QSCALE = 0.125f * 1.44269504089f;  // fold softmax scale into Q
        #pragma unroll
        for (int m = 0; m < 4; ++m) {
            const long gr = (long)bm * 128 + wm + m * 16 + rbase;
            #pragma unroll
            for (int n = 0; n < 4; ++n) {
                const int gc = bn * 128 + wn + n * 16 + lcol;
                const int nn = gc & 1023;
                const float bv_ = bias[nn];
                #pragma unroll
                for (int r = 0; r < 4; ++r) {
                    const long t = gr + r;
                    const float v = acc[m][n][r] + bv_;
                    if (which == 0)      outQ[t * 1024 + nn] = __float2bfloat16(v * QSCALE);
                    else if (which == 1) outK[t * 1024 + nn] = __float2bfloat16(v);
                    else {
                        const long bb = t >> 11;       // batch
                        const long s  = t & 2047;      // seq pos
                        const int  hh = nn >> 6, dh = nn & 63;
                        outVt[((bb * 16 + hh) * 64 + dh) * 2048 + s] = __float2bfloat16(v);
                    }
                }
            }
        }
    } else {
        #pragma unroll
        for (int m = 0; m < 4; ++m) {
            const long gr = (long)bm * 128 + wm + m * 16 + rbase;
            #pragma unroll
            for (int n = 0; n < 4; ++n) {
                const int gc = bn * 128 + wn + n * 16 + lcol;
                const float bv_ = bias0[gc];
                #pragma unroll
                for (int r = 0; r < 4; ++r) {
                    const long t = gr + r;
                    outO[t * 1024 + gc] = acc[m][n][r] + bv_ + xres[t * 1024 + gc];
                }
            }
        }
    }
}

// ---------------- causal flash attention v9 = v7 + HW exp2/cvt_pk --------------
// Sequential dual-halves (qt=pr then 31-pr), 128-k iterations, double-buffered
// 64KB swizzled LDS, T1 XCD remap (8 heads/XCD), K-row permutation for K=32 PV,
// fixed-m softmax, l via MFMA-vs-ONES. NEW: p=2^s via raw v_exp_f32 and P-pack
// via v_cvt_pk_bf16_f32 (1 instr each, replacing OCML exp2f + software-RNE
// __float2bfloat16 which inflated VALU ~460 instrs/subtile).
__global__ __launch_bounds__(256) void attn_kernel(
    const bf16* __restrict__ Qb, const bf16* __restrict__ Kb,
    const bf16* __restrict__ Vt, bf16* __restrict__ ctx)
{
    __shared__ __align__(16) bf16 Ks[2][2][4096];   // [buf][sub][64 rows x 64 cols]
    __shared__ __align__(16) bf16 Vs[2][2][4096];
    const int tid = threadIdx.x, wv = tid >> 6, lane = tid & 63;
    const int id  = blockIdx.y * 16 + blockIdx.x;   // physical dispatch order
    const int lid = (id & 7) * 128 + (id >> 3);     // XCD-chunked logical id
    const int bh  = lid >> 4;                       // 0..63 (8 heads per XCD)
    const int pr  = lid & 15;                       // 0..15
    const int b = bh >> 4, h = bh & 15;
    const bf16* Qh = Qb + (long)b * SEQ * DIM + h * 64;
    const bf16* Kh = Kb + (long)b * SEQ * DIM + h * 64;
    const bf16* Vh = Vt + (long)bh * 64 * SEQ;
    const int lcol = lane & 15;       // q (C col) / fragment row selector
    const int lrow = lane >> 4;       // 0..3
    const int l8 = lane >> 3, l7 = lane & 7;
    const int swz = (l7 ^ l8) * 8;
    const int kprow = (wv >> 1) * 32 + (l8 >> 2) * 8 + (wv & 1) * 4 + (l8 & 3); // i=0; +16 for i=1
    const bf16* kSrc = Kh + (long)kprow * DIM + swz;            // + (k + i*16)*DIM
    const bf16* vSrc = Vh + (long)(wv * 16 + l8) * SEQ + swz;   // + k + i*8*SEQ

    const bf16x8 ONES = { (short)0x3F80, (short)0x3F80, (short)0x3F80, (short)0x3F80,
                          (short)0x3F80, (short)0x3F80, (short)0x3F80, (short)0x3F80 };

    #pragma unroll
    for (int half = 0; half < 2; ++half) {
        const int qt = half ? (31 - pr) : pr;
        const int qtb = qt * 64;
        const int q0 = qtb + wv * 16;             // this wave's 16 q rows
        bf16x8 qf[2];
        #pragma unroll
        for (int kk = 0; kk < 2; ++kk)
            qf[kk] = *(const bf16x8*)&Qh[(long)(q0 + lcol) * DIM + kk * 32 + lrow * 8];

        f32x4 o_acc[4] = {};
        f32x4 l_acc = {};
        const int itn = (qt >> 1) + 1;            // 128-k iterations
        // prologue: stage iteration 0 into buffer 0
        #pragma unroll
        for (int sub = 0; sub < 2; ++sub) {
            char* dK = (char*)Ks[0][sub] + wv * 2048;
            char* dV = (char*)Vs[0][sub] + wv * 2048;
            #pragma unroll
            for (int i = 0; i < 2; ++i) {
                g2lds16(kSrc + (long)(sub * 64 + i * 16) * DIM, dK + i * 1024);
                g2lds16(vSrc + sub * 64 + (long)i * 8 * SEQ, dV + i * 1024);
            }
        }
        __syncthreads();
        for (int it = 0; it < itn; ++it) {
            // prefetch iteration it+1 into the other buffer
            if (it + 1 < itn) {
                const long ko = (long)(it + 1) * 128;
                #pragma unroll
                for (int sub = 0; sub < 2; ++sub) {
                    const bf16* kS = kSrc + (ko + sub * 64) * DIM;
                    const bf16* vS = vSrc + ko + sub * 64;
                    char* dK = (char*)Ks[(it + 1) & 1][sub] + wv * 2048;
                    char* dV = (char*)Vs[(it + 1) & 1][sub] + wv * 2048;
                    #pragma unroll
                    for (int i = 0; i < 2; ++i) {
                        g2lds16(kS + (long)i * 16 * DIM, dK + i * 1024);
                        g2lds16(vS + (long)i * 8 * SEQ, dV + i * 1024);
                    }
                }
            }
            #pragma unroll
            for (int sub = 0; sub < 2; ++sub) {
                const int kbase = it * 128 + sub * 64;
                if (kbase > qtb) continue;         // beyond causal frontier (uniform)
                const char* Kp = (const char*)Ks[it & 1][sub];
                const char* Vp = (const char*)Vs[it & 1][sub];
                // --- S^T sub-tile: mfma(K, Q), K-frag from swizzled LDS ---
                f32x4 s_acc[4] = {};
                __builtin_amdgcn_s_setprio(1);
                #pragma unroll
                for (int n = 0; n < 4; ++n) {
                    const int krow = n * 16 + lcol;
                    #pragma unroll
                    for (int kk = 0; kk < 2; ++kk) {
                        const int off = (krow * 128 + kk * 64 + lrow * 16) ^ ((krow & 7) << 4);
                        bf16x8 kf = *(const bf16x8*)(Kp + off);
                        s_acc[n] = __builtin_amdgcn_mfma_f32_16x16x32_bf16(kf, qf[kk], s_acc[n], 0, 0, 0);
                    }
                }
                __builtin_amdgcn_s_setprio(0);
                // --- causal mask (diagonal sub-tile only); s_acc[n][r] holds
                //     actual k = kbase + (n>>1)*32 + lrow*8 + (n&1)*4 + r ---
                if (kbase == qtb) {
                    const int qg = q0 + lcol;
                    #pragma unroll
                    for (int n = 0; n < 4; ++n)
                        #pragma unroll
                        for (int r = 0; r < 4; ++r) {
                            const int ka = kbase + ((n >> 1) << 5) + lrow * 8 + ((n & 1) << 2) + r;
                            if (ka > qg) s_acc[n][r] = -1e30f;
                        }
                }
                // --- fixed-m softmax numerator: p = 2^s (raw v_exp_f32) ---
                #pragma unroll
                for (int n = 0; n < 4; ++n)
                    #pragma unroll
                    for (int r = 0; r < 4; ++r)
                        s_acc[n][r] = hexp2(s_acc[n][r]);
                // --- pack P into two K=32 A-frags via v_cvt_pk_bf16_f32 ---
                union { unsigned u[4]; bf16x8 v; } pkA, pkB;
                pkA.u[0] = cvtpk(s_acc[0][0], s_acc[0][1]);
                pkA.u[1] = cvtpk(s_acc[0][2], s_acc[0][3]);
                pkA.u[2] = cvtpk(s_acc[1][0], s_acc[1][1]);
                pkA.u[3] = cvtpk(s_acc[1][2], s_acc[1][3]);
                pkB.u[0] = cvtpk(s_acc[2][0], s_acc[2][1]);
                pkB.u[1] = cvtpk(s_acc[2][2], s_acc[2][3]);
                pkB.u[2] = cvtpk(s_acc[3][0], s_acc[3][1]);
                pkB.u[3] = cvtpk(s_acc[3][2], s_acc[3][3]);
                const bf16x8 paA = pkA.v, paB = pkB.v;
                // --- PV + row-sum, all on the matrix pipe ---
                __builtin_amdgcn_s_setprio(1);
                l_acc = __builtin_amdgcn_mfma_f32_16x16x32_bf16(paA, ONES, l_acc, 0, 0, 0);
                l_acc = __builtin_amdgcn_mfma_f32_16x16x32_bf16(paB, ONES, l_acc, 0, 0, 0);
                #pragma unroll
                for (int d = 0; d < 4; ++d) {
                    const int vrow = d * 16 + lcol;
                    const int offA = (vrow * 128 + lrow * 16) ^ ((vrow & 7) << 4);
                    const int offB = offA ^ 64;   // +64B = k half 2 (bit 6 untouched by swizzle)
                    bf16x8 vfA = *(const bf16x8*)(Vp + offA);
                    o_acc[d] = __builtin_amdgcn_mfma_f32_16x16x32_bf16(paA, vfA, o_acc[d], 0, 0, 0);
                    bf16x8 vfB = *(const bf16x8*)(Vp + offB);
                    o_acc[d] = __builtin_amdgcn_mfma_f32_16x16x32_bf16(paB, vfB, o_acc[d], 0, 0, 0);
                }
                __builtin_amdgcn_s_setprio(0);
            }
            __syncthreads();   // readers of buf[it&1] done + staging of it+1 drained
        }
        // --- epilogue: l is in the same C-layout as o_acc -> lane-local divide ---
        #pragma unroll
        for (int d = 0; d < 4; ++d)
            #pragma unroll
            for (int r = 0; r < 4; ++r) {
                const float v = o_acc[d][r] / l_acc[r];
                ctx[(long)(b * SEQ + q0 + lrow * 4 + r) * DIM + h * 64 + d * 16 + lcol] = __float2bfloat16(v);
            }
    }
}

// ---------------- row LayerNorm, in place on d_out ----------------
__global__ __launch_bounds__(256) void ln_kernel(float* __restrict__ io,
    const float* __restrict__ gamma, const float* __restrict__ beta)
{
    float* p = io + (long)blockIdx.x * 1024;
    const int tid = threadIdx.x;
    const int c = tid * 4;
    const float4 v = *(const float4*)&p[c];
    float s  = v.x + v.y + v.z + v.w;
    float s2 = v.x * v.x + v.y * v.y + v.z * v.z + v.w * v.w;
    #pragma unroll
    for (int off = 1; off < 64; off <<= 1) {
        s  += __shfl_xor(s, off);
        s2 += __shfl_xor(s2, off);
    }
    __shared__ float red[8];
    if ((tid & 63) == 0) { red[tid >> 6] = s; red[4 + (tid >> 6)] = s2; }
    __syncthreads();
    s  = red[0] + red[1] + red[2] + red[3];
    s2 = red[4] + red[5] + red[6] + red[7];
    const float mu = s * (1.0f / 1024.0f);
    const float var = fmaxf(s2 * (1.0f / 1024.0f) - mu * mu, 0.0f);
    const float rstd = rsqrtf(var + 1e-5f);
    const float4 g  = *(const float4*)&gamma[c];
    const float4 bb = *(const float4*)&beta[c];
    float4 o;
    o.x = (v.x - mu) * rstd * g.x + bb.x;
    o.y = (v.y - mu) * rstd * g.y + bb.y;
    o.z = (v.z - mu) * rstd * g.z + bb.z;
    o.w = (v.w - mu) * rstd * g.w + bb.w;
    *(float4*)&p[c] = o;
}

extern "C" void kernel_launch(void* const* d_in, const int* in_sizes, int n_in,
                              void* d_out, int out_size, void* d_ws, size_t ws_size,
                              hipStream_t stream)
{
    const float* x     = (const float*)d_in[0];
    const float* Wq    = (const float*)d_in[1];
    const float* bq    = (const float*)d_in[2];
    const float* Wk    = (const float*)d_in[3];
    const float* bk    = (const float*)d_in[4];
    const float* Wv    = (const float*)d_in[5];
    const float* bv    = (const float*)d_in[6];
    const float* Wo    = (const float*)d_in[7];
    const float* bo    = (const float*)d_in[8];
    const float* gamma = (const float*)d_in[9];
    const float* beta  = (const float*)d_in[10];
    float* out = (float*)d_out;

    char* ws = (char*)d_ws;
    bf16* xb  = (bf16*)(ws);                          // 16 MB  x bf16 [8192,1024]
    bf16* wb  = (bf16*)(ws + (16L << 20));            //  8 MB  Wq,Wk,Wv,Wo bf16 stacked
    bf16* Qb  = (bf16*)(ws + (24L << 20));            // 16 MB  [8192,1024]
    bf16* Kb  = (bf16*)(ws + (40L << 20));            // 16 MB
    bf16* Vt  = (bf16*)(ws + (56L << 20));            // 16 MB  [64][64][2048]
    bf16* ctx = (bf16*)(ws + (72L << 20));            // 16 MB  [8192,1024]

    cast_all_kernel<<<12288, 256, 0, stream>>>(x, Wq, Wk, Wv, Wo, xb, wb);
    gemm_bt_kernel<0><<<dim3(64, 24), 256, 0, stream>>>(
        xb, wb, bq, bk, bv, nullptr, Qb, Kb, Vt, nullptr);
    attn_kernel<<<dim3(16, 64), 256, 0, stream>>>(Qb, Kb, Vt, ctx);
    gemm_bt_kernel<1><<<dim3(64, 8), 256, 0, stream>>>(
        ctx, wb + 3L * 1048576, bo, nullptr, nullptr, x, nullptr, nullptr, nullptr, out);
    ln_kernel<<<8192, 256, 0, stream>>>(out, gamma, beta);
}